// Round 2
// baseline (2547.630 us; speedup 1.0000x reference)
//
#include <hip/hip_runtime.h>
#include <hip/hip_bf16.h>

#define B_ 2
#define T_ 1024
#define D_ 6144
#define NQ_ 48
#define NKV_ 8
#define HD_ 128
#define GQ_ 6
#define MULT_ 0.08838834764831845f
#define MAXATTN_ 30.0f

typedef __bf16 bf8_t __attribute__((ext_vector_type(8)));
typedef short short8 __attribute__((ext_vector_type(8)));
typedef float f4 __attribute__((ext_vector_type(4)));

__device__ inline float b2f(unsigned short u) {
  return __uint_as_float(((unsigned int)u) << 16);
}
__device__ inline unsigned short f2b(float f) {
  unsigned int u = __float_as_uint(f);
  u += 0x7FFFu + ((u >> 16) & 1u);
  return (unsigned short)(u >> 16);
}
__device__ inline bf8_t ld_frag(const unsigned short* p) {
  return __builtin_bit_cast(bf8_t, *reinterpret_cast<const short8*>(p));
}
__device__ inline f4 mfma16x16(bf8_t a, bf8_t b, f4 c) {
  return __builtin_amdgcn_mfma_f32_16x16x32_bf16(a, b, c, 0, 0, 0);
}

// C[M,N] = A[M,K] @ W[K,N] + bias. A/W fp32 or bf16 per template; bf16 MFMA,
// fp32 accum. 64x64 tile per block, 4 waves; wave w: rows [16w,16w+16) x 64 cols.
template <int A_F32, int W_F32, int OUT_F32>
__global__ __launch_bounds__(256) void gemm_k(
    const void* __restrict__ Ap, const void* __restrict__ Wp,
    const float* __restrict__ bias, void* __restrict__ Cp,
    int M, int N, int K)
{
  __shared__ unsigned short As[64][32];   // [m][k]
  __shared__ unsigned short BsT[64][32];  // [n][k]
  const int tid = threadIdx.x;
  const int wave = tid >> 6;
  const int lane = tid & 63;
  const int quad = lane >> 4;
  const int l16 = lane & 15;
  const int m0 = blockIdx.y * 64;
  const int n0 = blockIdx.x * 64;

  const int la_row = tid >> 2;        // 0..63 (m)
  const int la_col = (tid & 3) * 8;   // 0,8,16,24 (k)
  const int lb_row = tid >> 3;        // 0..31 (k)
  const int lb_col = (tid & 7) * 8;   // 0..56 (n)

  f4 acc[4];
  #pragma unroll
  for (int i = 0; i < 4; i++) acc[i] = f4{0.f, 0.f, 0.f, 0.f};

  for (int k0 = 0; k0 < K; k0 += 32) {
    short8 av, bv;
    if constexpr (A_F32) {
      const float* pa = (const float*)Ap + (size_t)(m0 + la_row) * K + k0 + la_col;
      f4 x0 = *reinterpret_cast<const f4*>(pa);
      f4 x1 = *reinterpret_cast<const f4*>(pa + 4);
      #pragma unroll
      for (int i = 0; i < 4; i++) {
        av[i]     = (short)f2b(x0[i]);
        av[4 + i] = (short)f2b(x1[i]);
      }
    } else {
      const unsigned short* pa =
          (const unsigned short*)Ap + (size_t)(m0 + la_row) * K + k0 + la_col;
      av = *reinterpret_cast<const short8*>(pa);
    }
    if constexpr (W_F32) {
      const float* pb = (const float*)Wp + (size_t)(k0 + lb_row) * N + n0 + lb_col;
      f4 x0 = *reinterpret_cast<const f4*>(pb);
      f4 x1 = *reinterpret_cast<const f4*>(pb + 4);
      #pragma unroll
      for (int i = 0; i < 4; i++) {
        bv[i]     = (short)f2b(x0[i]);
        bv[4 + i] = (short)f2b(x1[i]);
      }
    } else {
      const unsigned short* pb =
          (const unsigned short*)Wp + (size_t)(k0 + lb_row) * N + n0 + lb_col;
      bv = *reinterpret_cast<const short8*>(pb);
    }
    *reinterpret_cast<short8*>(&As[la_row][la_col]) = av;
    #pragma unroll
    for (int i = 0; i < 8; i++) BsT[lb_col + i][lb_row] = (unsigned short)bv[i];
    __syncthreads();
    bf8_t afrag = ld_frag(&As[wave * 16 + l16][quad * 8]);
    #pragma unroll
    for (int nt = 0; nt < 4; nt++) {
      bf8_t bfrag = ld_frag(&BsT[nt * 16 + l16][quad * 8]);
      acc[nt] = mfma16x16(afrag, bfrag, acc[nt]);
    }
    __syncthreads();
  }

  #pragma unroll
  for (int nt = 0; nt < 4; nt++) {
    int gn = n0 + nt * 16 + l16;
    float bfv = bias ? bias[gn] : 0.f;
    #pragma unroll
    for (int r = 0; r < 4; r++) {
      int gm = m0 + wave * 16 + quad * 4 + r;
      float val = acc[nt][r] + bfv;
      if constexpr (OUT_F32) {
        ((float*)Cp)[(size_t)gm * N + gn] = val;
      } else {
        ((unsigned short*)Cp)[(size_t)gm * N + gn] = f2b(val);
      }
    }
  }
}

// In-place NeoX RoPE on bf16 X [B,T,nheads,HD]. One thread per (b,t,h,pair).
__global__ __launch_bounds__(256) void rope_k(unsigned short* __restrict__ X,
                                              int nheads, int total)
{
  int idx = blockIdx.x * 256 + threadIdx.x;
  if (idx >= total) return;
  int i = idx & 63;
  int rem = idx >> 6;                 // (b*T + t)*nheads + h
  int t = (rem / nheads) % T_;
  size_t base = (size_t)rem * HD_;
  float inv = expf(-9.210340371976184f * (float)(2 * i) * (1.0f / 128.0f));
  float ph = (float)t * inv;
  float sp, cp;
  sincosf(ph, &sp, &cp);
  float x1 = b2f(X[base + i]);
  float x2 = b2f(X[base + 64 + i]);
  X[base + i]      = f2b(x1 * cp - x2 * sp);
  X[base + 64 + i] = f2b(x2 * cp + x1 * sp);
}

// Flash attention: 4 independent waves/block, each owns 16 q-rows of one
// (b,h). Key tiles of 32, online softmax, tanh softcap, causal. bf16 in/out.
__global__ __launch_bounds__(256) void attn_k(
    const unsigned short* __restrict__ Q,   // [B,T,NQ,HD]
    const unsigned short* __restrict__ Kb,  // [B,T,NKV,HD]
    const unsigned short* __restrict__ Vb,  // [B,T,NKV,HD]
    unsigned short* __restrict__ O)         // [B,T,NQ,HD]
{
  __shared__ unsigned short Pls[4][16][32];
  const int tid = threadIdx.x;
  const int wave = tid >> 6;
  const int lane = tid & 63;
  const int quad = lane >> 4;
  const int l16 = lane & 15;
  const int b = blockIdx.z;
  const int h = blockIdx.y;
  const int hk = h / GQ_;
  const int t0 = blockIdx.x * 64 + wave * 16;

  bf8_t qf[4];
  {
    const unsigned short* qp =
        Q + ((size_t)(b * T_ + t0 + l16) * NQ_ + h) * HD_ + quad * 8;
    #pragma unroll
    for (int i = 0; i < 4; i++) qf[i] = ld_frag(qp + i * 32);
  }

  f4 accO[8];
  #pragma unroll
  for (int i = 0; i < 8; i++) accO[i] = f4{0.f, 0.f, 0.f, 0.f};
  float mrow[4] = {-1e30f, -1e30f, -1e30f, -1e30f};
  float lrow[4] = {0.f, 0.f, 0.f, 0.f};

  const int kend = t0 + 16;
  for (int t1 = 0; t1 < kend; t1 += 32) {
    f4 s0 = f4{0.f,0.f,0.f,0.f}, s1 = f4{0.f,0.f,0.f,0.f};
    {
      const unsigned short* kp0 =
          Kb + ((size_t)(b * T_ + t1 + l16) * NKV_ + hk) * HD_ + quad * 8;
      const unsigned short* kp1 = kp0 + 16 * NKV_ * HD_;
      #pragma unroll
      for (int i = 0; i < 4; i++) {
        s0 = mfma16x16(qf[i], ld_frag(kp0 + i * 32), s0);
        s1 = mfma16x16(qf[i], ld_frag(kp1 + i * 32), s1);
      }
    }
    #pragma unroll
    for (int r = 0; r < 4; r++) {
      int qg = t0 + quad * 4 + r;
      float v0 = s0[r] * MULT_;
      float v1 = s1[r] * MULT_;
      v0 = MAXATTN_ * tanhf(v0 * (1.0f / MAXATTN_));
      v1 = MAXATTN_ * tanhf(v1 * (1.0f / MAXATTN_));
      if (t1 + l16 > qg)      v0 = -1e30f;
      if (t1 + 16 + l16 > qg) v1 = -1e30f;
      float tmax = fmaxf(v0, v1);
      #pragma unroll
      for (int off = 1; off < 16; off <<= 1)
        tmax = fmaxf(tmax, __shfl_xor(tmax, off, 16));
      float mnew = fmaxf(mrow[r], tmax);
      float alpha = __expf(mrow[r] - mnew);
      float p0 = __expf(v0 - mnew);
      float p1 = __expf(v1 - mnew);
      float ps = p0 + p1;
      #pragma unroll
      for (int off = 1; off < 16; off <<= 1)
        ps += __shfl_xor(ps, off, 16);
      lrow[r] = lrow[r] * alpha + ps;
      mrow[r] = mnew;
      #pragma unroll
      for (int nt = 0; nt < 8; nt++) accO[nt][r] *= alpha;
      Pls[wave][quad * 4 + r][l16]      = f2b(p0);
      Pls[wave][quad * 4 + r][16 + l16] = f2b(p1);
    }
    __threadfence_block();
    bf8_t pfrag = ld_frag(&Pls[wave][l16][quad * 8]);
    const unsigned short* vp =
        Vb + ((size_t)(b * T_ + t1) * NKV_ + hk) * HD_ + l16;
    #pragma unroll
    for (int nt = 0; nt < 8; nt++) {
      short8 vv;
      #pragma unroll
      for (int j = 0; j < 8; j++)
        vv[j] = (short)vp[(size_t)(quad * 8 + j) * (NKV_ * HD_) + nt * 16];
      accO[nt] = mfma16x16(pfrag, __builtin_bit_cast(bf8_t, vv), accO[nt]);
    }
  }

  float invl[4];
  #pragma unroll
  for (int r = 0; r < 4; r++) invl[r] = 1.0f / lrow[r];
  #pragma unroll
  for (int nt = 0; nt < 8; nt++) {
    #pragma unroll
    for (int r = 0; r < 4; r++) {
      int tg = t0 + quad * 4 + r;
      O[((size_t)(b * T_ + tg) * NQ_ + h) * HD_ + nt * 16 + l16] =
          f2b(accO[nt][r] * invl[r]);
    }
  }
}

extern "C" void kernel_launch(void* const* d_in, const int* in_sizes, int n_in,
                              void* d_out, int out_size, void* d_ws, size_t ws_size,
                              hipStream_t stream)
{
  const float* q_in = (const float*)d_in[0];
  const float* k_in = (const float*)d_in[1];
  const float* v_in = (const float*)d_in[2];
  // d_in[3] = mask (causal tril) — hard-coded in attn_k
  const float* wq = (const float*)d_in[4];
  const float* bq = (const float*)d_in[5];
  const float* wk = (const float*)d_in[6];
  const float* bk = (const float*)d_in[7];
  const float* wv = (const float*)d_in[8];
  const float* bv = (const float*)d_in[9];
  const float* wo = (const float*)d_in[10];
  float* out = (float*)d_out;

  char* ws = (char*)d_ws;
  unsigned short* Qb = (unsigned short*)(ws);             // 25,165,824 B
  unsigned short* Kb = (unsigned short*)(ws + 25165824);  //  4,194,304 B
  unsigned short* Vb = (unsigned short*)(ws + 29360128);  //  4,194,304 B
  unsigned short* Ab = (unsigned short*)(ws + 33554432);  // 25,165,824 B

  const int M = B_ * T_;  // 2048
  dim3 blk(256);

  gemm_k<1,1,0><<<dim3(D_ / 64, M / 64), blk, 0, stream>>>(
      q_in, wq, bq, Qb, M, NQ_ * HD_, D_);
  gemm_k<1,1,0><<<dim3((NKV_ * HD_) / 64, M / 64), blk, 0, stream>>>(
      k_in, wk, bk, Kb, M, NKV_ * HD_, D_);
  gemm_k<1,1,0><<<dim3((NKV_ * HD_) / 64, M / 64), blk, 0, stream>>>(
      v_in, wv, bv, Vb, M, NKV_ * HD_, D_);

  rope_k<<<(B_ * T_ * NQ_ * 64) / 256, blk, 0, stream>>>(
      Qb, NQ_, B_ * T_ * NQ_ * 64);
  rope_k<<<(B_ * T_ * NKV_ * 64) / 256, blk, 0, stream>>>(
      Kb, NKV_, B_ * T_ * NKV_ * 64);

  attn_k<<<dim3(T_ / 64, NQ_, B_), blk, 0, stream>>>(Qb, Kb, Vb, Ab);

  gemm_k<0,1,1><<<dim3(D_ / 64, M / 64), blk, 0, stream>>>(
      Ab, wo, nullptr, out, M, D_, NQ_ * HD_);
}